// Round 1
// baseline (288.189 us; speedup 1.0000x reference)
//
#include <hip/hip_runtime.h>
#include <math.h>

#define N 8192
#define D_IN 3
#define D_K 128
#define HID 256
#define N_RES 2
#define N_TRI 2730
#define N_EDGE 2048
#define EPS 1.1920929e-07f

// ---------------- workspace layout (byte offsets, 256-aligned) ----------------
// attended : N*D_K floats  = 4,194,304 B
// logits   : N floats      = 32,768 B
// ex       : N floats      = 32,768 B
// seg_max  : N_EDGE floats = 8,192 B
// seg_sum  : N_EDGE floats = 8,192 B
// tri_count: N_TRI ints    -> pad 11,008 B
// tri_off  : N_TRI ints    -> pad 11,008 B
// tri_cur  : N_TRI ints    -> pad 11,008 B
// members  : N ints        = 32,768 B
#define OFF_ATT      0
#define OFF_LOGITS   (OFF_ATT + 4194304)
#define OFF_EX       (OFF_LOGITS + 32768)
#define OFF_SEGMAX   (OFF_EX + 32768)
#define OFF_SEGSUM   (OFF_SEGMAX + 8192)
#define OFF_TRICNT   (OFF_SEGSUM + 8192)
#define OFF_TRIOFF   (OFF_TRICNT + 11008)
#define OFF_TRICUR   (OFF_TRIOFF + 11008)
#define OFF_MEMBERS  (OFF_TRICUR + 11008)

__device__ __forceinline__ float atomicMaxFloat(float* addr, float value) {
    int* ai = (int*)addr;
    int old = __float_as_int(*addr);
    while (value > __int_as_float(old)) {
        int assumed = old;
        old = atomicCAS(ai, assumed, __float_as_int(value));
        if (old == assumed) break;
    }
    return __int_as_float(old);
}

__global__ void k_init(int* tri_count, float* seg_max, float* seg_sum) {
    int i = blockIdx.x * blockDim.x + threadIdx.x;
    if (i < N_TRI) tri_count[i] = 0;
    if (i < N_EDGE) { seg_max[i] = -INFINITY; seg_sum[i] = 0.f; }
}

__global__ void k_count(const int* tri, int* tri_count) {
    int n = blockIdx.x * blockDim.x + threadIdx.x;
    if (n < N) atomicAdd(&tri_count[tri[n]], 1);
}

#define SCAN_SIZE 4096
__global__ void k_scan(const int* tri_count, int* tri_offset, int* tri_cursor) {
    __shared__ int buf0[SCAN_SIZE];
    __shared__ int buf1[SCAN_SIZE];
    int t = threadIdx.x;  // 1024 threads
    for (int i = t; i < SCAN_SIZE; i += 1024) buf0[i] = (i < N_TRI) ? tri_count[i] : 0;
    __syncthreads();
    int* src = buf0; int* dst = buf1;
    for (int off = 1; off < SCAN_SIZE; off <<= 1) {
        for (int i = t; i < SCAN_SIZE; i += 1024) {
            int v = src[i];
            if (i >= off) v += src[i - off];
            dst[i] = v;
        }
        __syncthreads();
        int* tmp = src; src = dst; dst = tmp;
    }
    // src = inclusive scan
    for (int i = t; i < N_TRI; i += 1024) {
        int excl = (i == 0) ? 0 : src[i - 1];
        tri_offset[i] = excl;
        tri_cursor[i] = excl;
    }
}

__global__ void k_scatter(const int* tri, int* tri_cursor, int* members) {
    int n = blockIdx.x * blockDim.x + threadIdx.x;
    if (n < N) {
        int pos = atomicAdd(&tri_cursor[tri[n]], 1);
        members[pos] = n;
    }
}

// one wave (64 lanes) per row; 4 rows per 256-thread block
__global__ __launch_bounds__(256) void k_attn(
        const float* __restrict__ ef, const int* __restrict__ tri,
        const float* __restrict__ Wq, const float* __restrict__ bq,
        const float* __restrict__ Wk, const float* __restrict__ bk,
        const float* __restrict__ Wv, const float* __restrict__ bv,
        const int* __restrict__ tri_offset, const int* __restrict__ tri_count,
        const int* __restrict__ members, float* __restrict__ attended) {
    int wave = threadIdx.x >> 6;
    int lane = threadIdx.x & 63;
    int row = blockIdx.x * 4 + wave;
    int d0 = lane * 2, d1 = lane * 2 + 1;

    float e0 = ef[row * 3 + 0], e1 = ef[row * 3 + 1], e2 = ef[row * 3 + 2];
    float qa = bq[d0] + e0 * Wq[d0] + e1 * Wq[D_K + d0] + e2 * Wq[2 * D_K + d0];
    float qb = bq[d1] + e0 * Wq[d1] + e1 * Wq[D_K + d1] + e2 * Wq[2 * D_K + d1];

    int t = tri[row];
    int off = tri_offset[t], cnt = tri_count[t];
    const float scale = 0.08838834764831845f;  // 1/sqrt(128)

    float m = -INFINITY, l = 0.f, acca = 0.f, accb = 0.f;
    for (int ii = 0; ii < cnt; ++ii) {
        int j = members[off + ii];
        float f0 = ef[j * 3 + 0], f1 = ef[j * 3 + 1], f2 = ef[j * 3 + 2];
        float ka = bk[d0] + f0 * Wk[d0] + f1 * Wk[D_K + d0] + f2 * Wk[2 * D_K + d0];
        float kb = bk[d1] + f0 * Wk[d1] + f1 * Wk[D_K + d1] + f2 * Wk[2 * D_K + d1];
        float p = qa * ka + qb * kb;
        #pragma unroll
        for (int o = 32; o > 0; o >>= 1) p += __shfl_xor(p, o);
        float s = p * scale;
        float va = bv[d0] + f0 * Wv[d0] + f1 * Wv[D_K + d0] + f2 * Wv[2 * D_K + d0];
        float vb = bv[d1] + f0 * Wv[d1] + f1 * Wv[D_K + d1] + f2 * Wv[2 * D_K + d1];
        float mn = fmaxf(m, s);
        float sc = expf(m - mn);   // first iter: exp(-inf)=0
        float w  = expf(s - mn);
        l    = l * sc + w;
        acca = acca * sc + w * va;
        accb = accb * sc + w * vb;
        m = mn;
    }
    attended[row * D_K + d0] = acca / l;
    attended[row * D_K + d1] = accb / l;
}

// one 256-thread block per row: full MLP + resblocks + logit + seg max
__global__ __launch_bounds__(256) void k_mlp(
        const float* __restrict__ attended, const int* __restrict__ eids,
        const float* __restrict__ W0, const float* __restrict__ b0,
        const float* __restrict__ rms_w, const float* __restrict__ Wres,
        const float* __restrict__ bres, const float* __restrict__ Wout,
        const float* __restrict__ bout,
        float* __restrict__ logits, float* __restrict__ seg_max) {
    __shared__ float att[D_K];
    __shared__ float hn[HID];
    __shared__ float red[8];
    int row = blockIdx.x;
    int t = threadIdx.x;

    if (t < D_K) att[t] = attended[row * D_K + t];
    __syncthreads();

    float h = b0[t];
    #pragma unroll 4
    for (int k2 = 0; k2 < D_K; ++k2) h += att[k2] * W0[k2 * HID + t];

    for (int r = 0; r < N_RES; ++r) {
        float ss = h * h;
        #pragma unroll
        for (int o = 32; o > 0; o >>= 1) ss += __shfl_xor(ss, o);
        if ((t & 63) == 0) red[t >> 6] = ss;
        __syncthreads();
        float ms = (red[0] + red[1] + red[2] + red[3]) * (1.0f / HID);
        float hnv = h * rsqrtf(ms + EPS) * rms_w[r * HID + t];
        __syncthreads();   // all reads of red done before red reused next iter
        hn[t] = hnv;
        __syncthreads();
        float acc = bres[r * HID + t];
        const float* W = Wres + r * HID * HID;
        #pragma unroll 4
        for (int k2 = 0; k2 < HID; ++k2) acc += hn[k2] * W[k2 * HID + t];
        h = h + fmaxf(acc, 0.f);
        __syncthreads();   // hn reads done before next-iter writes
    }

    float ss = h * Wout[t];
    #pragma unroll
    for (int o = 32; o > 0; o >>= 1) ss += __shfl_xor(ss, o);
    if ((t & 63) == 0) red[t >> 6] = ss;
    __syncthreads();
    if (t == 0) {
        float logit = red[0] + red[1] + red[2] + red[3] + bout[0];
        logits[row] = logit;
        atomicMaxFloat(&seg_max[eids[row]], logit);
    }
}

__global__ void k_exp(const float* __restrict__ logits, const int* __restrict__ eids,
                      const float* __restrict__ seg_max, float* __restrict__ ex,
                      float* __restrict__ seg_sum) {
    int n = blockIdx.x * blockDim.x + threadIdx.x;
    if (n < N) {
        float e = expf(logits[n] - seg_max[eids[n]]);
        ex[n] = e;
        atomicAdd(&seg_sum[eids[n]], e);
    }
}

__global__ void k_norm(const float* __restrict__ ex, const int* __restrict__ eids,
                       const float* __restrict__ seg_sum, float* __restrict__ out) {
    int n = blockIdx.x * blockDim.x + threadIdx.x;
    if (n < N) out[n] = ex[n] / seg_sum[eids[n]];
}

extern "C" void kernel_launch(void* const* d_in, const int* in_sizes, int n_in,
                              void* d_out, int out_size, void* d_ws, size_t ws_size,
                              hipStream_t stream) {
    const float* ef   = (const float*)d_in[0];
    const int*   eids = (const int*)d_in[1];
    const int*   tri  = (const int*)d_in[2];
    const float* Wq = (const float*)d_in[3];
    const float* bq = (const float*)d_in[4];
    const float* Wk = (const float*)d_in[5];
    const float* bk = (const float*)d_in[6];
    const float* Wv = (const float*)d_in[7];
    const float* bv = (const float*)d_in[8];
    const float* W0 = (const float*)d_in[9];
    const float* b0 = (const float*)d_in[10];
    const float* rms_w = (const float*)d_in[11];
    const float* Wres  = (const float*)d_in[12];
    const float* bres  = (const float*)d_in[13];
    const float* Wout  = (const float*)d_in[14];
    const float* bout  = (const float*)d_in[15];
    float* out = (float*)d_out;

    char* ws = (char*)d_ws;
    float* attended  = (float*)(ws + OFF_ATT);
    float* logits    = (float*)(ws + OFF_LOGITS);
    float* ex        = (float*)(ws + OFF_EX);
    float* seg_max   = (float*)(ws + OFF_SEGMAX);
    float* seg_sum   = (float*)(ws + OFF_SEGSUM);
    int*   tri_count = (int*)(ws + OFF_TRICNT);
    int*   tri_off   = (int*)(ws + OFF_TRIOFF);
    int*   tri_cur   = (int*)(ws + OFF_TRICUR);
    int*   members   = (int*)(ws + OFF_MEMBERS);

    hipLaunchKernelGGL(k_init, dim3((N_TRI + 255) / 256), dim3(256), 0, stream,
                       tri_count, seg_max, seg_sum);
    hipLaunchKernelGGL(k_count, dim3(N / 256), dim3(256), 0, stream, tri, tri_count);
    hipLaunchKernelGGL(k_scan, dim3(1), dim3(1024), 0, stream, tri_count, tri_off, tri_cur);
    hipLaunchKernelGGL(k_scatter, dim3(N / 256), dim3(256), 0, stream, tri, tri_cur, members);
    hipLaunchKernelGGL(k_attn, dim3(N / 4), dim3(256), 0, stream,
                       ef, tri, Wq, bq, Wk, bk, Wv, bv, tri_off, tri_count, members, attended);
    hipLaunchKernelGGL(k_mlp, dim3(N), dim3(256), 0, stream,
                       attended, eids, W0, b0, rms_w, Wres, bres, Wout, bout, logits, seg_max);
    hipLaunchKernelGGL(k_exp, dim3(N / 256), dim3(256), 0, stream,
                       logits, eids, seg_max, ex, seg_sum);
    hipLaunchKernelGGL(k_norm, dim3(N / 256), dim3(256), 0, stream,
                       ex, eids, seg_sum, out);
}

// Round 2
// 217.309 us; speedup vs baseline: 1.3262x; 1.3262x over previous
//
#include <hip/hip_runtime.h>
#include <math.h>

#define N 8192
#define D_IN 3
#define D_K 128
#define HID 256
#define N_RES 2
#define N_TRI 2730
#define N_EDGE 2048
#define EPS 1.1920929e-07f

#define OFF_ATT      0
#define OFF_LOGITS   (OFF_ATT + 4194304)
#define OFF_EX       (OFF_LOGITS + 32768)
#define OFF_SEGMAX   (OFF_EX + 32768)
#define OFF_SEGSUM   (OFF_SEGMAX + 8192)
#define OFF_TRICNT   (OFF_SEGSUM + 8192)
#define OFF_TRIOFF   (OFF_TRICNT + 11008)
#define OFF_TRICUR   (OFF_TRIOFF + 11008)
#define OFF_MEMBERS  (OFF_TRICUR + 11008)

__device__ __forceinline__ float atomicMaxFloat(float* addr, float value) {
    int* ai = (int*)addr;
    int old = __float_as_int(*addr);
    while (value > __int_as_float(old)) {
        int assumed = old;
        old = atomicCAS(ai, assumed, __float_as_int(value));
        if (old == assumed) break;
    }
    return __int_as_float(old);
}

__global__ void k_init(int* tri_count, float* seg_max, float* seg_sum) {
    int i = blockIdx.x * blockDim.x + threadIdx.x;
    if (i < N_TRI) tri_count[i] = 0;
    if (i < N_EDGE) { seg_max[i] = -INFINITY; seg_sum[i] = 0.f; }
}

__global__ void k_count(const int* tri, int* tri_count) {
    int n = blockIdx.x * blockDim.x + threadIdx.x;
    if (n < N) atomicAdd(&tri_count[tri[n]], 1);
}

#define SCAN_SIZE 4096
__global__ void k_scan(const int* tri_count, int* tri_offset, int* tri_cursor) {
    __shared__ int buf0[SCAN_SIZE];
    __shared__ int buf1[SCAN_SIZE];
    int t = threadIdx.x;  // 1024 threads
    for (int i = t; i < SCAN_SIZE; i += 1024) buf0[i] = (i < N_TRI) ? tri_count[i] : 0;
    __syncthreads();
    int* src = buf0; int* dst = buf1;
    for (int off = 1; off < SCAN_SIZE; off <<= 1) {
        for (int i = t; i < SCAN_SIZE; i += 1024) {
            int v = src[i];
            if (i >= off) v += src[i - off];
            dst[i] = v;
        }
        __syncthreads();
        int* tmp = src; src = dst; dst = tmp;
    }
    for (int i = t; i < N_TRI; i += 1024) {
        int excl = (i == 0) ? 0 : src[i - 1];
        tri_offset[i] = excl;
        tri_cursor[i] = excl;
    }
}

__global__ void k_scatter(const int* tri, int* tri_cursor, int* members) {
    int n = blockIdx.x * blockDim.x + threadIdx.x;
    if (n < N) {
        int pos = atomicAdd(&tri_cursor[tri[n]], 1);
        members[pos] = n;
    }
}

// one wave (64 lanes) per row; 4 rows per 256-thread block
__global__ __launch_bounds__(256) void k_attn(
        const float* __restrict__ ef, const int* __restrict__ tri,
        const float* __restrict__ Wq, const float* __restrict__ bq,
        const float* __restrict__ Wk, const float* __restrict__ bk,
        const float* __restrict__ Wv, const float* __restrict__ bv,
        const int* __restrict__ tri_offset, const int* __restrict__ tri_count,
        const int* __restrict__ members, float* __restrict__ attended) {
    int wave = threadIdx.x >> 6;
    int lane = threadIdx.x & 63;
    int row = blockIdx.x * 4 + wave;
    int d0 = lane * 2, d1 = lane * 2 + 1;

    float e0 = ef[row * 3 + 0], e1 = ef[row * 3 + 1], e2 = ef[row * 3 + 2];
    float qa = bq[d0] + e0 * Wq[d0] + e1 * Wq[D_K + d0] + e2 * Wq[2 * D_K + d0];
    float qb = bq[d1] + e0 * Wq[d1] + e1 * Wq[D_K + d1] + e2 * Wq[2 * D_K + d1];

    int t = tri[row];
    int off = tri_offset[t], cnt = tri_count[t];
    const float scale = 0.08838834764831845f;  // 1/sqrt(128)

    float m = -INFINITY, l = 0.f, acca = 0.f, accb = 0.f;
    for (int ii = 0; ii < cnt; ++ii) {
        int j = members[off + ii];
        float f0 = ef[j * 3 + 0], f1 = ef[j * 3 + 1], f2 = ef[j * 3 + 2];
        float ka = bk[d0] + f0 * Wk[d0] + f1 * Wk[D_K + d0] + f2 * Wk[2 * D_K + d0];
        float kb = bk[d1] + f0 * Wk[d1] + f1 * Wk[D_K + d1] + f2 * Wk[2 * D_K + d1];
        float p = qa * ka + qb * kb;
        #pragma unroll
        for (int o = 32; o > 0; o >>= 1) p += __shfl_xor(p, o);
        float s = p * scale;
        float va = bv[d0] + f0 * Wv[d0] + f1 * Wv[D_K + d0] + f2 * Wv[2 * D_K + d0];
        float vb = bv[d1] + f0 * Wv[d1] + f1 * Wv[D_K + d1] + f2 * Wv[2 * D_K + d1];
        float mn = fmaxf(m, s);
        float sc = expf(m - mn);
        float w  = expf(s - mn);
        l    = l * sc + w;
        acca = acca * sc + w * va;
        accb = accb * sc + w * vb;
        m = mn;
    }
    attended[row * D_K + d0] = acca / l;
    attended[row * D_K + d1] = accb / l;
}

#define XC(v,i) ((i)==0?(v).x:((i)==1?(v).y:((i)==2?(v).z:(v).w)))

// Register-tiled MLP: 4 waves/block, 8 rows/wave, 4 cols/lane.
// Weight reads amortized 8x per wave (32x per block via L1 reuse).
__global__ __launch_bounds__(256) void k_mlp(
        const float* __restrict__ attended, const int* __restrict__ eids,
        const float* __restrict__ W0, const float* __restrict__ b0,
        const float* __restrict__ rms_w, const float* __restrict__ Wres,
        const float* __restrict__ bres, const float* __restrict__ Wout,
        const float* __restrict__ bout,
        float* __restrict__ logits, float* __restrict__ seg_max) {
    __shared__ float x_lds[4 * 8 * 256];   // 32 KB: per-wave 8x256 activations
    const int wave = threadIdx.x >> 6;
    const int lane = threadIdx.x & 63;
    const int c0 = lane * 4;               // this lane's 4 output columns
    const int base_row = blockIdx.x * 32 + wave * 8;
    float* xw = &x_lds[wave * 2048];

    // stage attended rows (8 x 128 floats) into per-wave LDS
    #pragma unroll
    for (int rr = 0; rr < 4; ++rr) {
        int r = rr * 2 + (lane >> 5);
        int kk = (lane & 31) * 4;
        *(float4*)&xw[r * 256 + kk] =
            *(const float4*)&attended[(base_row + r) * D_K + kk];
    }
    __syncthreads();

    float h[8][4];
    // ---- layer 0: [8 x 128] @ [128 x 256] + b0 ----
    {
        float4 bb = *(const float4*)&b0[c0];
        #pragma unroll
        for (int r = 0; r < 8; ++r) { h[r][0]=bb.x; h[r][1]=bb.y; h[r][2]=bb.z; h[r][3]=bb.w; }
        for (int k = 0; k < D_K; k += 4) {
            float4 wv[4];
            #pragma unroll
            for (int i = 0; i < 4; ++i) wv[i] = *(const float4*)&W0[(k + i) * HID + c0];
            #pragma unroll
            for (int r = 0; r < 8; ++r) {
                float4 xr = *(const float4*)&xw[r * 256 + k];
                #pragma unroll
                for (int i = 0; i < 4; ++i) {
                    float xs = XC(xr, i);
                    h[r][0] += xs * wv[i].x;
                    h[r][1] += xs * wv[i].y;
                    h[r][2] += xs * wv[i].z;
                    h[r][3] += xs * wv[i].w;
                }
            }
        }
    }

    // ---- resblocks ----
    for (int ir = 0; ir < N_RES; ++ir) {
        float part[8];
        #pragma unroll
        for (int r = 0; r < 8; ++r)
            part[r] = h[r][0]*h[r][0] + h[r][1]*h[r][1] + h[r][2]*h[r][2] + h[r][3]*h[r][3];
        #pragma unroll
        for (int o = 32; o > 0; o >>= 1) {
            #pragma unroll
            for (int r = 0; r < 8; ++r) part[r] += __shfl_xor(part[r], o);
        }
        float4 g = *(const float4*)&rms_w[ir * HID + c0];
        #pragma unroll
        for (int r = 0; r < 8; ++r) {
            float s = rsqrtf(part[r] * (1.0f / HID) + EPS);
            float4 hn;
            hn.x = h[r][0] * s * g.x;
            hn.y = h[r][1] * s * g.y;
            hn.z = h[r][2] * s * g.z;
            hn.w = h[r][3] * s * g.w;
            *(float4*)&xw[r * 256 + c0] = hn;
        }
        __syncthreads();

        const float* W = Wres + ir * HID * HID;
        float4 bb = *(const float4*)&bres[ir * HID + c0];
        float a2[8][4];
        #pragma unroll
        for (int r = 0; r < 8; ++r) { a2[r][0]=bb.x; a2[r][1]=bb.y; a2[r][2]=bb.z; a2[r][3]=bb.w; }
        for (int k = 0; k < HID; k += 4) {
            float4 wv[4];
            #pragma unroll
            for (int i = 0; i < 4; ++i) wv[i] = *(const float4*)&W[(k + i) * HID + c0];
            #pragma unroll
            for (int r = 0; r < 8; ++r) {
                float4 xr = *(const float4*)&xw[r * 256 + k];
                #pragma unroll
                for (int i = 0; i < 4; ++i) {
                    float xs = XC(xr, i);
                    a2[r][0] += xs * wv[i].x;
                    a2[r][1] += xs * wv[i].y;
                    a2[r][2] += xs * wv[i].z;
                    a2[r][3] += xs * wv[i].w;
                }
            }
        }
        #pragma unroll
        for (int r = 0; r < 8; ++r) {
            h[r][0] += fmaxf(a2[r][0], 0.f);
            h[r][1] += fmaxf(a2[r][1], 0.f);
            h[r][2] += fmaxf(a2[r][2], 0.f);
            h[r][3] += fmaxf(a2[r][3], 0.f);
        }
        __syncthreads();   // xw reads done before next-iteration writes
    }

    // ---- logits + segment max ----
    {
        float4 wo = *(const float4*)&Wout[c0];
        float part[8];
        #pragma unroll
        for (int r = 0; r < 8; ++r)
            part[r] = h[r][0]*wo.x + h[r][1]*wo.y + h[r][2]*wo.z + h[r][3]*wo.w;
        #pragma unroll
        for (int o = 32; o > 0; o >>= 1) {
            #pragma unroll
            for (int r = 0; r < 8; ++r) part[r] += __shfl_xor(part[r], o);
        }
        if (lane == 0) {
            float bo = bout[0];
            #pragma unroll
            for (int r = 0; r < 8; ++r) {
                int row = base_row + r;
                float lg = part[r] + bo;
                logits[row] = lg;
                atomicMaxFloat(&seg_max[eids[row]], lg);
            }
        }
    }
}

__global__ void k_exp(const float* __restrict__ logits, const int* __restrict__ eids,
                      const float* __restrict__ seg_max, float* __restrict__ ex,
                      float* __restrict__ seg_sum) {
    int n = blockIdx.x * blockDim.x + threadIdx.x;
    if (n < N) {
        float e = expf(logits[n] - seg_max[eids[n]]);
        ex[n] = e;
        atomicAdd(&seg_sum[eids[n]], e);
    }
}

__global__ void k_norm(const float* __restrict__ ex, const int* __restrict__ eids,
                       const float* __restrict__ seg_sum, float* __restrict__ out) {
    int n = blockIdx.x * blockDim.x + threadIdx.x;
    if (n < N) out[n] = ex[n] / seg_sum[eids[n]];
}

extern "C" void kernel_launch(void* const* d_in, const int* in_sizes, int n_in,
                              void* d_out, int out_size, void* d_ws, size_t ws_size,
                              hipStream_t stream) {
    const float* ef   = (const float*)d_in[0];
    const int*   eids = (const int*)d_in[1];
    const int*   tri  = (const int*)d_in[2];
    const float* Wq = (const float*)d_in[3];
    const float* bq = (const float*)d_in[4];
    const float* Wk = (const float*)d_in[5];
    const float* bk = (const float*)d_in[6];
    const float* Wv = (const float*)d_in[7];
    const float* bv = (const float*)d_in[8];
    const float* W0 = (const float*)d_in[9];
    const float* b0 = (const float*)d_in[10];
    const float* rms_w = (const float*)d_in[11];
    const float* Wres  = (const float*)d_in[12];
    const float* bres  = (const float*)d_in[13];
    const float* Wout  = (const float*)d_in[14];
    const float* bout  = (const float*)d_in[15];
    float* out = (float*)d_out;

    char* ws = (char*)d_ws;
    float* attended  = (float*)(ws + OFF_ATT);
    float* logits    = (float*)(ws + OFF_LOGITS);
    float* ex        = (float*)(ws + OFF_EX);
    float* seg_max   = (float*)(ws + OFF_SEGMAX);
    float* seg_sum   = (float*)(ws + OFF_SEGSUM);
    int*   tri_count = (int*)(ws + OFF_TRICNT);
    int*   tri_off   = (int*)(ws + OFF_TRIOFF);
    int*   tri_cur   = (int*)(ws + OFF_TRICUR);
    int*   members   = (int*)(ws + OFF_MEMBERS);

    hipLaunchKernelGGL(k_init, dim3((N_TRI + 255) / 256), dim3(256), 0, stream,
                       tri_count, seg_max, seg_sum);
    hipLaunchKernelGGL(k_count, dim3(N / 256), dim3(256), 0, stream, tri, tri_count);
    hipLaunchKernelGGL(k_scan, dim3(1), dim3(1024), 0, stream, tri_count, tri_off, tri_cur);
    hipLaunchKernelGGL(k_scatter, dim3(N / 256), dim3(256), 0, stream, tri, tri_cur, members);
    hipLaunchKernelGGL(k_attn, dim3(N / 4), dim3(256), 0, stream,
                       ef, tri, Wq, bq, Wk, bk, Wv, bv, tri_off, tri_count, members, attended);
    hipLaunchKernelGGL(k_mlp, dim3(N / 32), dim3(256), 0, stream,
                       attended, eids, W0, b0, rms_w, Wres, bres, Wout, bout, logits, seg_max);
    hipLaunchKernelGGL(k_exp, dim3(N / 256), dim3(256), 0, stream,
                       logits, eids, seg_max, ex, seg_sum);
    hipLaunchKernelGGL(k_norm, dim3(N / 256), dim3(256), 0, stream,
                       ex, eids, seg_sum, out);
}

// Round 3
// 183.150 us; speedup vs baseline: 1.5735x; 1.1865x over previous
//
#include <hip/hip_runtime.h>
#include <math.h>

#define N 8192
#define D_IN 3
#define D_K 128
#define HID 256
#define N_RES 2
#define N_TRI 2730
#define N_EDGE 2048
#define EPS 1.1920929e-07f

#define OFF_ATT      0
#define OFF_LOGITS   (OFF_ATT + 4194304)
#define OFF_EX       (OFF_LOGITS + 32768)
#define OFF_SEGMAX   (OFF_EX + 32768)
#define OFF_SEGSUM   (OFF_SEGMAX + 8192)
#define OFF_TRICNT   (OFF_SEGSUM + 8192)
#define OFF_TRIOFF   (OFF_TRICNT + 11008)
#define OFF_TRICUR   (OFF_TRIOFF + 11008)
#define OFF_MEMBERS  (OFF_TRICUR + 11008)

__device__ __forceinline__ float atomicMaxFloat(float* addr, float value) {
    int* ai = (int*)addr;
    int old = __float_as_int(*addr);
    while (value > __int_as_float(old)) {
        int assumed = old;
        old = atomicCAS(ai, assumed, __float_as_int(value));
        if (old == assumed) break;
    }
    return __int_as_float(old);
}

__global__ void k_init(int* tri_count, float* seg_max, float* seg_sum) {
    int i = blockIdx.x * blockDim.x + threadIdx.x;
    if (i < N_TRI) tri_count[i] = 0;
    if (i < N_EDGE) { seg_max[i] = -INFINITY; seg_sum[i] = 0.f; }
}

__global__ void k_count(const int* tri, int* tri_count) {
    int n = blockIdx.x * blockDim.x + threadIdx.x;
    if (n < N) atomicAdd(&tri_count[tri[n]], 1);
}

#define SCAN_SIZE 4096
__global__ void k_scan(const int* tri_count, int* tri_offset, int* tri_cursor) {
    __shared__ int buf0[SCAN_SIZE];
    __shared__ int buf1[SCAN_SIZE];
    int t = threadIdx.x;  // 1024 threads
    for (int i = t; i < SCAN_SIZE; i += 1024) buf0[i] = (i < N_TRI) ? tri_count[i] : 0;
    __syncthreads();
    int* src = buf0; int* dst = buf1;
    for (int off = 1; off < SCAN_SIZE; off <<= 1) {
        for (int i = t; i < SCAN_SIZE; i += 1024) {
            int v = src[i];
            if (i >= off) v += src[i - off];
            dst[i] = v;
        }
        __syncthreads();
        int* tmp = src; src = dst; dst = tmp;
    }
    for (int i = t; i < N_TRI; i += 1024) {
        int excl = (i == 0) ? 0 : src[i - 1];
        tri_offset[i] = excl;
        tri_cursor[i] = excl;
    }
}

__global__ void k_scatter(const int* tri, int* tri_cursor, int* members) {
    int n = blockIdx.x * blockDim.x + threadIdx.x;
    if (n < N) {
        int pos = atomicAdd(&tri_cursor[tri[n]], 1);
        members[pos] = n;
    }
}

// one wave (64 lanes) per row; 4 rows per 256-thread block
__global__ __launch_bounds__(256) void k_attn(
        const float* __restrict__ ef, const int* __restrict__ tri,
        const float* __restrict__ Wq, const float* __restrict__ bq,
        const float* __restrict__ Wk, const float* __restrict__ bk,
        const float* __restrict__ Wv, const float* __restrict__ bv,
        const int* __restrict__ tri_offset, const int* __restrict__ tri_count,
        const int* __restrict__ members, float* __restrict__ attended) {
    int wave = threadIdx.x >> 6;
    int lane = threadIdx.x & 63;
    int row = blockIdx.x * 4 + wave;
    int d0 = lane * 2, d1 = lane * 2 + 1;

    float e0 = ef[row * 3 + 0], e1 = ef[row * 3 + 1], e2 = ef[row * 3 + 2];
    float qa = bq[d0] + e0 * Wq[d0] + e1 * Wq[D_K + d0] + e2 * Wq[2 * D_K + d0];
    float qb = bq[d1] + e0 * Wq[d1] + e1 * Wq[D_K + d1] + e2 * Wq[2 * D_K + d1];

    int t = tri[row];
    int off = tri_offset[t], cnt = tri_count[t];
    const float scale = 0.08838834764831845f;  // 1/sqrt(128)

    float m = -INFINITY, l = 0.f, acca = 0.f, accb = 0.f;
    for (int ii = 0; ii < cnt; ++ii) {
        int j = members[off + ii];
        float f0 = ef[j * 3 + 0], f1 = ef[j * 3 + 1], f2 = ef[j * 3 + 2];
        float ka = bk[d0] + f0 * Wk[d0] + f1 * Wk[D_K + d0] + f2 * Wk[2 * D_K + d0];
        float kb = bk[d1] + f0 * Wk[d1] + f1 * Wk[D_K + d1] + f2 * Wk[2 * D_K + d1];
        float p = qa * ka + qb * kb;
        #pragma unroll
        for (int o = 32; o > 0; o >>= 1) p += __shfl_xor(p, o);
        float s = p * scale;
        float va = bv[d0] + f0 * Wv[d0] + f1 * Wv[D_K + d0] + f2 * Wv[2 * D_K + d0];
        float vb = bv[d1] + f0 * Wv[d1] + f1 * Wv[D_K + d1] + f2 * Wv[2 * D_K + d1];
        float mn = fmaxf(m, s);
        float sc = expf(m - mn);
        float w  = expf(s - mn);
        l    = l * sc + w;
        acca = acca * sc + w * va;
        accb = accb * sc + w * vb;
        m = mn;
    }
    attended[row * D_K + d0] = acca / l;
    attended[row * D_K + d1] = accb / l;
}

// Register-tiled MLP: 4 waves/block, each wave = 8 rows x 128 cols (2 cols/lane).
// Block covers 16 rows x 256 cols; grid = N/16 = 512 -> 2 blocks/CU, 8 waves/CU.
__global__ __launch_bounds__(256) void k_mlp(
        const float* __restrict__ attended, const int* __restrict__ eids,
        const float* __restrict__ W0, const float* __restrict__ b0,
        const float* __restrict__ rms_w, const float* __restrict__ Wres,
        const float* __restrict__ bres, const float* __restrict__ Wout,
        const float* __restrict__ bout,
        float* __restrict__ logits, float* __restrict__ seg_max) {
    __shared__ float x_lds[2][8][256];   // 16 KB: activations per row-group
    __shared__ float red[2][2][8];       // [rowgrp][colhalf][row] partial sums
    const int wave = threadIdx.x >> 6;
    const int lane = threadIdx.x & 63;
    const int rg = wave & 1;             // row group (rows rg*8 .. rg*8+7)
    const int ch = wave >> 1;            // column half
    const int c0 = ch * 128 + lane * 2;  // this lane's 2 output columns
    const int base_row = blockIdx.x * 16 + rg * 8;

    // stage 16 rows x 128 floats of attended into LDS (coalesced)
    {
        int f = threadIdx.x * 8;             // 256 threads x 8 floats = 2048
        int r = f >> 7, kk = f & 127;
        const float* src = attended + (size_t)(blockIdx.x * 16 + r) * D_K + kk;
        *(float4*)&x_lds[r >> 3][r & 7][kk]     = *(const float4*)&src[0];
        *(float4*)&x_lds[r >> 3][r & 7][kk + 4] = *(const float4*)&src[4];
    }
    __syncthreads();

    float h[8][2];
    // ---- layer 0: [8 x 128] @ [128 x 256] + b0 ----
    {
        float2 bb = *(const float2*)&b0[c0];
        #pragma unroll
        for (int r = 0; r < 8; ++r) { h[r][0] = bb.x; h[r][1] = bb.y; }
        for (int k = 0; k < D_K; k += 4) {
            float2 wv[4];
            #pragma unroll
            for (int i = 0; i < 4; ++i) wv[i] = *(const float2*)&W0[(k + i) * HID + c0];
            #pragma unroll
            for (int r = 0; r < 8; ++r) {
                float4 xr = *(const float4*)&x_lds[rg][r][k];
                h[r][0] += xr.x * wv[0].x; h[r][1] += xr.x * wv[0].y;
                h[r][0] += xr.y * wv[1].x; h[r][1] += xr.y * wv[1].y;
                h[r][0] += xr.z * wv[2].x; h[r][1] += xr.z * wv[2].y;
                h[r][0] += xr.w * wv[3].x; h[r][1] += xr.w * wv[3].y;
            }
        }
    }

    // ---- resblocks ----
    for (int ir = 0; ir < N_RES; ++ir) {
        __syncthreads();   // (A) all x_lds reads of previous GEMM done
        float part[8];
        #pragma unroll
        for (int r = 0; r < 8; ++r) part[r] = h[r][0] * h[r][0] + h[r][1] * h[r][1];
        #pragma unroll
        for (int o = 32; o > 0; o >>= 1) {
            #pragma unroll
            for (int r = 0; r < 8; ++r) part[r] += __shfl_xor(part[r], o);
        }
        if (lane == 0) {
            #pragma unroll
            for (int r = 0; r < 8; ++r) red[rg][ch][r] = part[r];
        }
        __syncthreads();   // (B) red visible
        float2 g = *(const float2*)&rms_w[ir * HID + c0];
        #pragma unroll
        for (int r = 0; r < 8; ++r) {
            float ms = (red[rg][0][r] + red[rg][1][r]) * (1.0f / HID);
            float s = rsqrtf(ms + EPS);
            float2 hn;
            hn.x = h[r][0] * s * g.x;
            hn.y = h[r][1] * s * g.y;
            *(float2*)&x_lds[rg][r][c0] = hn;
        }
        __syncthreads();   // (C) hn visible to both column-half waves

        const float* W = Wres + ir * HID * HID;
        float2 bb = *(const float2*)&bres[ir * HID + c0];
        float a2[8][2];
        #pragma unroll
        for (int r = 0; r < 8; ++r) { a2[r][0] = bb.x; a2[r][1] = bb.y; }
        for (int k = 0; k < HID; k += 4) {
            float2 wv[4];
            #pragma unroll
            for (int i = 0; i < 4; ++i) wv[i] = *(const float2*)&W[(k + i) * HID + c0];
            #pragma unroll
            for (int r = 0; r < 8; ++r) {
                float4 xr = *(const float4*)&x_lds[rg][r][k];
                a2[r][0] += xr.x * wv[0].x; a2[r][1] += xr.x * wv[0].y;
                a2[r][0] += xr.y * wv[1].x; a2[r][1] += xr.y * wv[1].y;
                a2[r][0] += xr.z * wv[2].x; a2[r][1] += xr.z * wv[2].y;
                a2[r][0] += xr.w * wv[3].x; a2[r][1] += xr.w * wv[3].y;
            }
        }
        #pragma unroll
        for (int r = 0; r < 8; ++r) {
            h[r][0] += fmaxf(a2[r][0], 0.f);
            h[r][1] += fmaxf(a2[r][1], 0.f);
        }
    }

    // ---- logits + segment max ----
    {
        float2 wo = *(const float2*)&Wout[c0];
        float part[8];
        #pragma unroll
        for (int r = 0; r < 8; ++r) part[r] = h[r][0] * wo.x + h[r][1] * wo.y;
        #pragma unroll
        for (int o = 32; o > 0; o >>= 1) {
            #pragma unroll
            for (int r = 0; r < 8; ++r) part[r] += __shfl_xor(part[r], o);
        }
        if (lane == 0) {
            #pragma unroll
            for (int r = 0; r < 8; ++r) red[rg][ch][r] = part[r];
        }
        __syncthreads();
        if (ch == 0 && lane == 0) {
            float bo = bout[0];
            #pragma unroll
            for (int r = 0; r < 8; ++r) {
                int row = base_row + r;
                float lg = red[rg][0][r] + red[rg][1][r] + bo;
                logits[row] = lg;
                atomicMaxFloat(&seg_max[eids[row]], lg);
            }
        }
    }
}

__global__ void k_exp(const float* __restrict__ logits, const int* __restrict__ eids,
                      const float* __restrict__ seg_max, float* __restrict__ ex,
                      float* __restrict__ seg_sum) {
    int n = blockIdx.x * blockDim.x + threadIdx.x;
    if (n < N) {
        float e = expf(logits[n] - seg_max[eids[n]]);
        ex[n] = e;
        atomicAdd(&seg_sum[eids[n]], e);
    }
}

__global__ void k_norm(const float* __restrict__ ex, const int* __restrict__ eids,
                       const float* __restrict__ seg_sum, float* __restrict__ out) {
    int n = blockIdx.x * blockDim.x + threadIdx.x;
    if (n < N) out[n] = ex[n] / seg_sum[eids[n]];
}

extern "C" void kernel_launch(void* const* d_in, const int* in_sizes, int n_in,
                              void* d_out, int out_size, void* d_ws, size_t ws_size,
                              hipStream_t stream) {
    const float* ef   = (const float*)d_in[0];
    const int*   eids = (const int*)d_in[1];
    const int*   tri  = (const int*)d_in[2];
    const float* Wq = (const float*)d_in[3];
    const float* bq = (const float*)d_in[4];
    const float* Wk = (const float*)d_in[5];
    const float* bk = (const float*)d_in[6];
    const float* Wv = (const float*)d_in[7];
    const float* bv = (const float*)d_in[8];
    const float* W0 = (const float*)d_in[9];
    const float* b0 = (const float*)d_in[10];
    const float* rms_w = (const float*)d_in[11];
    const float* Wres  = (const float*)d_in[12];
    const float* bres  = (const float*)d_in[13];
    const float* Wout  = (const float*)d_in[14];
    const float* bout  = (const float*)d_in[15];
    float* out = (float*)d_out;

    char* ws = (char*)d_ws;
    float* attended  = (float*)(ws + OFF_ATT);
    float* logits    = (float*)(ws + OFF_LOGITS);
    float* ex        = (float*)(ws + OFF_EX);
    float* seg_max   = (float*)(ws + OFF_SEGMAX);
    float* seg_sum   = (float*)(ws + OFF_SEGSUM);
    int*   tri_count = (int*)(ws + OFF_TRICNT);
    int*   tri_off   = (int*)(ws + OFF_TRIOFF);
    int*   tri_cur   = (int*)(ws + OFF_TRICUR);
    int*   members   = (int*)(ws + OFF_MEMBERS);

    hipLaunchKernelGGL(k_init, dim3((N_TRI + 255) / 256), dim3(256), 0, stream,
                       tri_count, seg_max, seg_sum);
    hipLaunchKernelGGL(k_count, dim3(N / 256), dim3(256), 0, stream, tri, tri_count);
    hipLaunchKernelGGL(k_scan, dim3(1), dim3(1024), 0, stream, tri_count, tri_off, tri_cur);
    hipLaunchKernelGGL(k_scatter, dim3(N / 256), dim3(256), 0, stream, tri, tri_cur, members);
    hipLaunchKernelGGL(k_attn, dim3(N / 4), dim3(256), 0, stream,
                       ef, tri, Wq, bq, Wk, bk, Wv, bv, tri_off, tri_count, members, attended);
    hipLaunchKernelGGL(k_mlp, dim3(N / 16), dim3(256), 0, stream,
                       attended, eids, W0, b0, rms_w, Wres, bres, Wout, bout, logits, seg_max);
    hipLaunchKernelGGL(k_exp, dim3(N / 256), dim3(256), 0, stream,
                       logits, eids, seg_max, ex, seg_sum);
    hipLaunchKernelGGL(k_norm, dim3(N / 256), dim3(256), 0, stream,
                       ex, eids, seg_sum, out);
}

// Round 4
// 128.531 us; speedup vs baseline: 2.2422x; 1.4249x over previous
//
#include <hip/hip_runtime.h>
#include <math.h>

#define N 8192
#define D_IN 3
#define D_K 128
#define HID 256
#define N_RES 2
#define N_TRI 2730
#define N_EDGE 2048
#define EPS 1.1920929e-07f

typedef unsigned short u16;
typedef float f32x4 __attribute__((ext_vector_type(4)));
typedef short s16x8 __attribute__((ext_vector_type(8)));

// ---------------- workspace layout ----------------
#define OFF_ATTB     0                        // N*128 bf16 = 2,097,152 B
#define OFF_LOGITS   2097152                  // N fp32 = 32,768 B
#define OFF_TRIOFF   (OFF_LOGITS + 32768)     // 11,008 B
#define OFF_TRICNT   (OFF_TRIOFF + 11008)     // 11,008 B
#define OFF_MEMT     (OFF_TRICNT + 11008)     // 32,768 B
#define OFF_EOFF     (OFF_MEMT + 32768)       // 8,192 B
#define OFF_ECNT     (OFF_EOFF + 8192)        // 8,192 B
#define OFF_MEME     (OFF_ECNT + 8192)        // 32,768 B
#define OFF_WPK      (OFF_MEME + 32768)       // 163840 bf16 = 327,680 B

__device__ __forceinline__ u16 f2bf(float f) {   // RTNE fp32 -> bf16
    unsigned int u = __float_as_uint(f);
    unsigned int r = (u + 0x7fffu + ((u >> 16) & 1u)) >> 16;
    return (u16)r;
}

// ---- fused prep: bucket rows by triangle_id AND edge_id (one block) ----
__global__ __launch_bounds__(1024) void k_prep(
        const int* __restrict__ tri, const int* __restrict__ eids,
        int* __restrict__ tri_off, int* __restrict__ tri_cnt, int* __restrict__ mem_t,
        int* __restrict__ e_off, int* __restrict__ e_cnt, int* __restrict__ mem_e) {
    __shared__ int sa[4096], sb[4096];
    __shared__ int ea[2048], eb[2048];
    const int t = threadIdx.x;
    for (int i = t; i < 4096; i += 1024) sa[i] = 0;
    for (int i = t; i < 2048; i += 1024) ea[i] = 0;
    __syncthreads();
    for (int n = t; n < N; n += 1024) {
        atomicAdd(&sa[tri[n]], 1);
        atomicAdd(&ea[eids[n]], 1);
    }
    __syncthreads();
    // inclusive scan of sa (4096, 12 steps) and ea (2048, 11 steps)
    int *src = sa, *dst = sb;
    for (int off = 1; off < 4096; off <<= 1) {
        for (int i = t; i < 4096; i += 1024) {
            int v = src[i];
            if (i >= off) v += src[i - off];
            dst[i] = v;
        }
        __syncthreads();
        int* tmp = src; src = dst; dst = tmp;
    }
    int *es = ea, *ed = eb;
    for (int off = 1; off < 2048; off <<= 1) {
        for (int i = t; i < 2048; i += 1024) {
            int v = es[i];
            if (i >= off) v += es[i - off];
            ed[i] = v;
        }
        __syncthreads();
        int* tmp = es; es = ed; ed = tmp;
    }
    // src = tri inclusive scan, dst = free (use as cursors); es/ed likewise
    for (int i = t; i < N_TRI; i += 1024) {
        int excl = i ? src[i - 1] : 0;
        tri_off[i] = excl;
        tri_cnt[i] = src[i] - excl;
        dst[i] = excl;
    }
    for (int i = t; i < N_EDGE; i += 1024) {
        int excl = i ? es[i - 1] : 0;
        e_off[i] = excl;
        e_cnt[i] = es[i] - excl;
        ed[i] = excl;
    }
    __syncthreads();
    for (int n = t; n < N; n += 1024) {
        int p = atomicAdd(&dst[tri[n]], 1);
        mem_t[p] = n;
        int q = atomicAdd(&ed[eids[n]], 1);
        mem_e[q] = n;
    }
}

// ---- pack weights fp32 -> bf16 in MFMA B-fragment order ----
// tile index within layer = nt*KT + kt; lane holds B[k=kt*32+(lane>>4)*8+j][n=nt*16+(lane&15)]
__global__ __launch_bounds__(256) void k_pack(
        const float* __restrict__ W0, const float* __restrict__ Wres,
        u16* __restrict__ Wpk) {
    int tid = blockIdx.x * 256 + threadIdx.x;   // 320 tiles * 64 lanes = 20480
    int tile = tid >> 6, lane = tid & 63;
    int q = lane >> 4, c = lane & 15;
    u16 tmp[8];
    int dst;
    if (tile < 64) {                 // layer0: KT=4, NT=16
        int nt = tile >> 2, kt = tile & 3;
        int k0 = kt * 32 + q * 8, n = nt * 16 + c;
        dst = (tile * 64 + lane) * 8;
        #pragma unroll
        for (int j = 0; j < 8; ++j) tmp[j] = f2bf(W0[(k0 + j) * HID + n]);
    } else {                         // res layers: KT=8, NT=16
        int t2 = tile - 64;
        int r = t2 >> 7, tl = t2 & 127;
        int nt = tl >> 3, kt = tl & 7;
        int k0 = kt * 32 + q * 8, n = nt * 16 + c;
        dst = 32768 + r * 65536 + (tl * 64 + lane) * 8;
        const float* W = Wres + r * 65536;
        #pragma unroll
        for (int j = 0; j < 8; ++j) tmp[j] = f2bf(W[(k0 + j) * HID + n]);
    }
    *(s16x8*)&Wpk[dst] = *(s16x8*)tmp;
}

// ---- attention: one wave per row, block-diagonal online softmax ----
__global__ __launch_bounds__(256) void k_attn(
        const float* __restrict__ ef, const int* __restrict__ tri,
        const float* __restrict__ Wq, const float* __restrict__ bq,
        const float* __restrict__ Wk, const float* __restrict__ bk,
        const float* __restrict__ Wv, const float* __restrict__ bv,
        const int* __restrict__ tri_offset, const int* __restrict__ tri_count,
        const int* __restrict__ members, u16* __restrict__ att) {
    int wave = threadIdx.x >> 6;
    int lane = threadIdx.x & 63;
    int row = blockIdx.x * 4 + wave;
    int d0 = lane * 2, d1 = lane * 2 + 1;

    float e0 = ef[row * 3 + 0], e1 = ef[row * 3 + 1], e2 = ef[row * 3 + 2];
    float qa = bq[d0] + e0 * Wq[d0] + e1 * Wq[D_K + d0] + e2 * Wq[2 * D_K + d0];
    float qb = bq[d1] + e0 * Wq[d1] + e1 * Wq[D_K + d1] + e2 * Wq[2 * D_K + d1];

    int t = tri[row];
    int off = tri_offset[t], cnt = tri_count[t];
    const float scale = 0.08838834764831845f;  // 1/sqrt(128)

    float m = -INFINITY, l = 0.f, acca = 0.f, accb = 0.f;
    for (int ii = 0; ii < cnt; ++ii) {
        int j = members[off + ii];
        float f0 = ef[j * 3 + 0], f1 = ef[j * 3 + 1], f2 = ef[j * 3 + 2];
        float ka = bk[d0] + f0 * Wk[d0] + f1 * Wk[D_K + d0] + f2 * Wk[2 * D_K + d0];
        float kb = bk[d1] + f0 * Wk[d1] + f1 * Wk[D_K + d1] + f2 * Wk[2 * D_K + d1];
        float p = qa * ka + qb * kb;
        #pragma unroll
        for (int o = 32; o > 0; o >>= 1) p += __shfl_xor(p, o);
        float s = p * scale;
        float va = bv[d0] + f0 * Wv[d0] + f1 * Wv[D_K + d0] + f2 * Wv[2 * D_K + d0];
        float vb = bv[d1] + f0 * Wv[d1] + f1 * Wv[D_K + d1] + f2 * Wv[2 * D_K + d1];
        float mn = fmaxf(m, s);
        float sc = expf(m - mn);
        float w  = expf(s - mn);
        l    = l * sc + w;
        acca = acca * sc + w * va;
        accb = accb * sc + w * vb;
        m = mn;
    }
    att[row * D_K + d0] = f2bf(acca / l);
    att[row * D_K + d1] = f2bf(accb / l);
}

// ---- MFMA MLP: 16 rows/block, 4 waves; wave w owns cols w*64..w*64+63 ----
__global__ __launch_bounds__(256) void k_mlp(
        const u16* __restrict__ att,
        const float* __restrict__ b0, const float* __restrict__ rms_w,
        const float* __restrict__ bres, const float* __restrict__ Wout,
        const float* __restrict__ bout, const u16* __restrict__ Wpk,
        float* __restrict__ logits) {
    __shared__ u16 X[16][264];     // +8 pad -> conflict-free b128 A-frag reads
    __shared__ float red[4][16];
    const int tid = threadIdx.x;
    const int w = tid >> 6, lane = tid & 63;
    const int q = lane >> 4, c = lane & 15;
    const int base = blockIdx.x * 16;
    const int colb = w * 64 + c;

    // stage attended (bf16) 16 x 128 into LDS
    {
        int r = tid >> 4, kk = (tid & 15) * 8;
        *(s16x8*)&X[r][kk] = *(const s16x8*)&att[(base + r) * D_K + kk];
    }
    __syncthreads();

    const s16x8* Bp = (const s16x8*)Wpk;    // one s16x8 per (tile,lane)

    float h[4][4];      // [nt][reg]: row q*4+reg, col colb+nt*16
    f32x4 acc[4];
    const f32x4 zero = {0.f, 0.f, 0.f, 0.f};

    // ---- layer0: [16x128] @ [128x256], K-tiles = 4 ----
    #pragma unroll
    for (int nt = 0; nt < 4; ++nt) acc[nt] = zero;
    for (int kt = 0; kt < 4; ++kt) {
        s16x8 a = *(const s16x8*)&X[c][kt * 32 + q * 8];
        #pragma unroll
        for (int nt = 0; nt < 4; ++nt) {
            s16x8 b = Bp[((w * 4 + nt) * 4 + kt) * 64 + lane];
            acc[nt] = __builtin_amdgcn_mfma_f32_16x16x32_bf16(a, b, acc[nt], 0, 0, 0);
        }
    }
    #pragma unroll
    for (int nt = 0; nt < 4; ++nt) {
        float bb = b0[colb + nt * 16];
        #pragma unroll
        for (int rg = 0; rg < 4; ++rg) h[nt][rg] = acc[nt][rg] + bb;
    }

    // ---- res blocks ----
    for (int ir = 0; ir < N_RES; ++ir) {
        float part[4];
        #pragma unroll
        for (int rg = 0; rg < 4; ++rg) {
            part[rg] = h[0][rg] * h[0][rg] + h[1][rg] * h[1][rg]
                     + h[2][rg] * h[2][rg] + h[3][rg] * h[3][rg];
            #pragma unroll
            for (int o = 1; o < 16; o <<= 1) part[rg] += __shfl_xor(part[rg], o);
        }
        if (c == 0) {
            #pragma unroll
            for (int rg = 0; rg < 4; ++rg) red[w][q * 4 + rg] = part[rg];
        }
        __syncthreads();   // red visible; all waves past previous X reads
        float sc[4];
        #pragma unroll
        for (int rg = 0; rg < 4; ++rg) {
            int rr = q * 4 + rg;
            float ms = (red[0][rr] + red[1][rr] + red[2][rr] + red[3][rr]) * (1.f / HID);
            sc[rg] = rsqrtf(ms + EPS);
        }
        #pragma unroll
        for (int nt = 0; nt < 4; ++nt) {
            float gg = rms_w[ir * HID + colb + nt * 16];
            #pragma unroll
            for (int rg = 0; rg < 4; ++rg) {
                X[q * 4 + rg][colb + nt * 16] = f2bf(h[nt][rg] * sc[rg] * gg);
            }
        }
        __syncthreads();   // hn visible

        const s16x8* Br = Bp + 4096 + ir * 8192;   // 32768/8 + ir*65536/8
        #pragma unroll
        for (int nt = 0; nt < 4; ++nt) acc[nt] = zero;
        for (int kt = 0; kt < 8; ++kt) {
            s16x8 a = *(const s16x8*)&X[c][kt * 32 + q * 8];
            #pragma unroll
            for (int nt = 0; nt < 4; ++nt) {
                s16x8 b = Br[((w * 4 + nt) * 8 + kt) * 64 + lane];
                acc[nt] = __builtin_amdgcn_mfma_f32_16x16x32_bf16(a, b, acc[nt], 0, 0, 0);
            }
        }
        #pragma unroll
        for (int nt = 0; nt < 4; ++nt) {
            float bb = bres[ir * HID + colb + nt * 16];
            #pragma unroll
            for (int rg = 0; rg < 4; ++rg) h[nt][rg] += fmaxf(acc[nt][rg] + bb, 0.f);
        }
    }

    // ---- logits ----
    {
        float wo[4];
        #pragma unroll
        for (int nt = 0; nt < 4; ++nt) wo[nt] = Wout[colb + nt * 16];
        float part[4];
        #pragma unroll
        for (int rg = 0; rg < 4; ++rg) {
            part[rg] = h[0][rg] * wo[0] + h[1][rg] * wo[1]
                     + h[2][rg] * wo[2] + h[3][rg] * wo[3];
            #pragma unroll
            for (int o = 1; o < 16; o <<= 1) part[rg] += __shfl_xor(part[rg], o);
        }
        if (c == 0) {
            #pragma unroll
            for (int rg = 0; rg < 4; ++rg) red[w][q * 4 + rg] = part[rg];
        }
        __syncthreads();
        if (tid < 16)
            logits[base + tid] = red[0][tid] + red[1][tid] + red[2][tid] + red[3][tid] + bout[0];
    }
}

// ---- scatter-softmax over edge buckets: one wave per edge ----
__global__ __launch_bounds__(256) void k_segsoft(
        const float* __restrict__ logits, const int* __restrict__ e_off,
        const int* __restrict__ e_cnt, const int* __restrict__ mem_e,
        float* __restrict__ out) {
    int e = (blockIdx.x * 256 + threadIdx.x) >> 6;
    int lane = threadIdx.x & 63;
    int off = e_off[e], cnt = e_cnt[e];
    float mx = -INFINITY;
    for (int i = lane; i < cnt; i += 64) mx = fmaxf(mx, logits[mem_e[off + i]]);
    #pragma unroll
    for (int o = 32; o > 0; o >>= 1) mx = fmaxf(mx, __shfl_xor(mx, o));
    float s = 0.f;
    for (int i = lane; i < cnt; i += 64) s += expf(logits[mem_e[off + i]] - mx);
    #pragma unroll
    for (int o = 32; o > 0; o >>= 1) s += __shfl_xor(s, o);
    float inv = 1.f / s;
    for (int i = lane; i < cnt; i += 64) {
        int m = mem_e[off + i];
        out[m] = expf(logits[m] - mx) * inv;
    }
}

extern "C" void kernel_launch(void* const* d_in, const int* in_sizes, int n_in,
                              void* d_out, int out_size, void* d_ws, size_t ws_size,
                              hipStream_t stream) {
    const float* ef   = (const float*)d_in[0];
    const int*   eids = (const int*)d_in[1];
    const int*   tri  = (const int*)d_in[2];
    const float* Wq = (const float*)d_in[3];
    const float* bq = (const float*)d_in[4];
    const float* Wk = (const float*)d_in[5];
    const float* bk = (const float*)d_in[6];
    const float* Wv = (const float*)d_in[7];
    const float* bv = (const float*)d_in[8];
    const float* W0 = (const float*)d_in[9];
    const float* b0 = (const float*)d_in[10];
    const float* rms_w = (const float*)d_in[11];
    const float* Wres  = (const float*)d_in[12];
    const float* bres  = (const float*)d_in[13];
    const float* Wout  = (const float*)d_in[14];
    const float* bout  = (const float*)d_in[15];
    float* out = (float*)d_out;

    char* ws = (char*)d_ws;
    u16*   attb    = (u16*)(ws + OFF_ATTB);
    float* logits  = (float*)(ws + OFF_LOGITS);
    int*   tri_off = (int*)(ws + OFF_TRIOFF);
    int*   tri_cnt = (int*)(ws + OFF_TRICNT);
    int*   mem_t   = (int*)(ws + OFF_MEMT);
    int*   e_off   = (int*)(ws + OFF_EOFF);
    int*   e_cnt   = (int*)(ws + OFF_ECNT);
    int*   mem_e   = (int*)(ws + OFF_MEME);
    u16*   Wpk     = (u16*)(ws + OFF_WPK);

    hipLaunchKernelGGL(k_prep, dim3(1), dim3(1024), 0, stream,
                       tri, eids, tri_off, tri_cnt, mem_t, e_off, e_cnt, mem_e);
    hipLaunchKernelGGL(k_pack, dim3(80), dim3(256), 0, stream, W0, Wres, Wpk);
    hipLaunchKernelGGL(k_attn, dim3(N / 4), dim3(256), 0, stream,
                       ef, tri, Wq, bq, Wk, bk, Wv, bv, tri_off, tri_cnt, mem_t, attb);
    hipLaunchKernelGGL(k_mlp, dim3(N / 16), dim3(256), 0, stream,
                       attb, b0, rms_w, bres, Wout, bout, Wpk, logits);
    hipLaunchKernelGGL(k_segsoft, dim3(N_EDGE / 4), dim3(256), 0, stream,
                       logits, e_off, e_cnt, mem_e, out);
}

// Round 5
// 118.002 us; speedup vs baseline: 2.4422x; 1.0892x over previous
//
#include <hip/hip_runtime.h>
#include <math.h>

#define N 8192
#define D_IN 3
#define D_K 128
#define HID 256
#define N_RES 2
#define N_TRI 2730
#define N_EDGE 2048
#define EPS 1.1920929e-07f

typedef unsigned short u16;
typedef unsigned int u32;
typedef float f32x4 __attribute__((ext_vector_type(4)));
typedef short s16x8 __attribute__((ext_vector_type(8)));

// ---------------- workspace layout ----------------
#define OFF_LOGITS   0                        // N fp32 = 32,768 B
#define OFF_TRIOFF   32768                    // 11,008 B
#define OFF_TRICNT   43776                    // 11,008 B
#define OFF_MEMT     54784                    // 32,768 B
#define OFF_EOFF     87552                    // 8,192 B
#define OFF_ECNT     95744                    // 8,192 B
#define OFF_MEME     103936                   // 32,768 B
#define OFF_WPK      136704                   // 163,840 bf16 = 327,680 B

__device__ __forceinline__ u16 f2bf(float f) {   // RTNE fp32 -> bf16
    u32 u = __float_as_uint(f);
    u32 r = (u + 0x7fffu + ((u >> 16) & 1u)) >> 16;
    return (u16)r;
}
__device__ __forceinline__ u32 pack2bf(float a, float b) {
    return (u32)f2bf(a) | ((u32)f2bf(b) << 16);
}

// ---- setup: block 0 = bucket rows by tri & edge; blocks 1..20 = pack weights ----
__global__ __launch_bounds__(1024) void k_setup(
        const int* __restrict__ tri, const int* __restrict__ eids,
        const float* __restrict__ W0, const float* __restrict__ Wres,
        int* __restrict__ tri_off, int* __restrict__ tri_cnt, int* __restrict__ mem_t,
        int* __restrict__ e_off, int* __restrict__ e_cnt, int* __restrict__ mem_e,
        u16* __restrict__ Wpk) {
    if (blockIdx.x != 0) {
        // ---- weight pack: 320 tiles x 64 lanes ----
        int tg = (blockIdx.x - 1) * 1024 + threadIdx.x;   // 0..20479
        int tile = tg >> 6, lane = tg & 63;
        int q = lane >> 4, c = lane & 15;
        u16 tmp[8];
        int dst;
        if (tile < 64) {                 // layer0: tile = nt*4 + kt
            int nt = tile >> 2, kt = tile & 3;
            int k0 = kt * 32 + q * 8, n = nt * 16 + c;
            dst = (tile * 64 + lane) * 8;
            #pragma unroll
            for (int j = 0; j < 8; ++j) tmp[j] = f2bf(W0[(k0 + j) * HID + n]);
        } else {                         // res layers: tl = nt*8 + kt
            int t2 = tile - 64;
            int r = t2 >> 7, tl = t2 & 127;
            int nt = tl >> 3, kt = tl & 7;
            int k0 = kt * 32 + q * 8, n = nt * 16 + c;
            dst = 32768 + r * 65536 + (tl * 64 + lane) * 8;
            const float* W = Wres + r * 65536;
            #pragma unroll
            for (int j = 0; j < 8; ++j) tmp[j] = f2bf(W[(k0 + j) * HID + n]);
        }
        *(s16x8*)&Wpk[dst] = *(s16x8*)tmp;
        return;
    }
    // ---- prep (one block, 1024 threads, shfl-hierarchical scans) ----
    __shared__ int sc[4096];
    __shared__ int ec[2048];
    __shared__ int wp[16];
    const int t = threadIdx.x, lane = t & 63, wid = t >> 6;
    for (int i = t; i < 4096; i += 1024) sc[i] = 0;
    for (int i = t; i < 2048; i += 1024) ec[i] = 0;
    __syncthreads();
    for (int n = t; n < N; n += 1024) {
        atomicAdd(&sc[tri[n]], 1);
        atomicAdd(&ec[eids[n]], 1);
    }
    __syncthreads();
    // tri scan: 4 elements/thread
    int a0 = sc[t*4], a1 = sc[t*4+1], a2 = sc[t*4+2], a3 = sc[t*4+3];
    int c0 = a0, c1 = c0 + a1, c2 = c1 + a2, c3 = c2 + a3;
    int ts = c3;
    #pragma unroll
    for (int o = 1; o < 64; o <<= 1) { int u = __shfl_up(ts, o); if (lane >= o) ts += u; }
    if (lane == 63) wp[wid] = ts;
    __syncthreads();
    if (wid == 0) {
        int v = (lane < 16) ? wp[lane] : 0;
        #pragma unroll
        for (int o = 1; o < 16; o <<= 1) { int u = __shfl_up(v, o); if (lane >= o) v += u; }
        if (lane < 16) wp[lane] = v;
    }
    __syncthreads();
    {
        int wexcl = wid ? wp[wid - 1] : 0;
        int texcl = wexcl + ts - c3;
        int o0 = texcl, o1 = texcl + c0, o2 = texcl + c1, o3 = texcl + c2;
        if (t*4+0 < N_TRI) { tri_off[t*4+0] = o0; tri_cnt[t*4+0] = a0; }
        if (t*4+1 < N_TRI) { tri_off[t*4+1] = o1; tri_cnt[t*4+1] = a1; }
        if (t*4+2 < N_TRI) { tri_off[t*4+2] = o2; tri_cnt[t*4+2] = a2; }
        if (t*4+3 < N_TRI) { tri_off[t*4+3] = o3; tri_cnt[t*4+3] = a3; }
        sc[t*4+0] = o0; sc[t*4+1] = o1; sc[t*4+2] = o2; sc[t*4+3] = o3;   // cursors
    }
    __syncthreads();   // wp reuse + cursor visibility
    // edge scan: 2 elements/thread
    int ea0 = ec[t*2], ea1 = ec[t*2+1];
    int f0 = ea0, f1 = f0 + ea1;
    int es = f1;
    #pragma unroll
    for (int o = 1; o < 64; o <<= 1) { int u = __shfl_up(es, o); if (lane >= o) es += u; }
    if (lane == 63) wp[wid] = es;
    __syncthreads();
    if (wid == 0) {
        int v = (lane < 16) ? wp[lane] : 0;
        #pragma unroll
        for (int o = 1; o < 16; o <<= 1) { int u = __shfl_up(v, o); if (lane >= o) v += u; }
        if (lane < 16) wp[lane] = v;
    }
    __syncthreads();
    {
        int wexcl = wid ? wp[wid - 1] : 0;
        int texcl = wexcl + es - f1;
        int eo0 = texcl, eo1 = texcl + f0;
        e_off[t*2+0] = eo0; e_cnt[t*2+0] = ea0;
        e_off[t*2+1] = eo1; e_cnt[t*2+1] = ea1;
        ec[t*2+0] = eo0; ec[t*2+1] = eo1;   // cursors
    }
    __syncthreads();
    for (int n = t; n < N; n += 1024) {
        int p = atomicAdd(&sc[tri[n]], 1);
        mem_t[p] = n;
        int q2 = atomicAdd(&ec[eids[n]], 1);
        mem_e[q2] = n;
    }
}

// ---- fused attention + MFMA MLP: 16 rows/block, 512 threads (8 waves) ----
// wave w owns cols w*32 + {0..15, 16..31}; attn phase: wave w computes rows 2w, 2w+1.
__global__ __launch_bounds__(512) void k_fused(
        const float* __restrict__ ef, const int* __restrict__ tri,
        const float* __restrict__ Wq, const float* __restrict__ bq,
        const float* __restrict__ Wk, const float* __restrict__ bk,
        const float* __restrict__ Wv, const float* __restrict__ bv,
        const int* __restrict__ tri_off, const int* __restrict__ tri_cnt,
        const int* __restrict__ mem_t,
        const float* __restrict__ b0, const float* __restrict__ rms_w,
        const float* __restrict__ bres, const float* __restrict__ Wout,
        const float* __restrict__ bout, const u16* __restrict__ Wpk,
        float* __restrict__ logits) {
    __shared__ u16 X[16][264];
    __shared__ float red[8][16];
    const int tid = threadIdx.x;
    const int w = tid >> 6, lane = tid & 63;
    const int q = lane >> 4, c = lane & 15;
    const int base = blockIdx.x * 16;
    const int colb = w * 32 + c;

    // ================= attention phase =================
    {
        const int d0 = lane * 2, d1 = d0 + 1;
        // hoist per-lane weight columns (reused for both rows)
        float wq0a = Wq[d0], wq1a = Wq[D_K + d0], wq2a = Wq[2*D_K + d0], bqa = bq[d0];
        float wq0b = Wq[d1], wq1b = Wq[D_K + d1], wq2b = Wq[2*D_K + d1], bqb = bq[d1];
        float wk0a = Wk[d0], wk1a = Wk[D_K + d0], wk2a = Wk[2*D_K + d0], bka = bk[d0];
        float wk0b = Wk[d1], wk1b = Wk[D_K + d1], wk2b = Wk[2*D_K + d1], bkb = bk[d1];
        float wv0a = Wv[d0], wv1a = Wv[D_K + d0], wv2a = Wv[2*D_K + d0], bva = bv[d0];
        float wv0b = Wv[d1], wv1b = Wv[D_K + d1], wv2b = Wv[2*D_K + d1], bvb = bv[d1];
        const float scale = 0.08838834764831845f;  // 1/sqrt(128)

        #pragma unroll
        for (int rr = 0; rr < 2; ++rr) {
            int lrow = 2 * w + rr;
            int row = base + lrow;
            float e0 = ef[row*3+0], e1 = ef[row*3+1], e2 = ef[row*3+2];
            float qa = bqa + e0*wq0a + e1*wq1a + e2*wq2a;
            float qb = bqb + e0*wq0b + e1*wq1b + e2*wq2b;
            int tt = tri[row];
            int off = tri_off[tt], cnt = tri_cnt[tt];
            float m = -INFINITY, l = 0.f, acca = 0.f, accb = 0.f;
            for (int bs = 0; bs < cnt; bs += 64) {
                int nn = cnt - bs; if (nn > 64) nn = 64;
                // lane-parallel member + feature gather (no serial dependent loads)
                float g0 = 0.f, g1 = 0.f, g2 = 0.f;
                if (lane < nn) {
                    int j = mem_t[off + bs + lane];
                    g0 = ef[j*3+0]; g1 = ef[j*3+1]; g2 = ef[j*3+2];
                }
                for (int ii = 0; ii < nn; ++ii) {
                    float h0 = __shfl(g0, ii), h1 = __shfl(g1, ii), h2 = __shfl(g2, ii);
                    float ka = bka + h0*wk0a + h1*wk1a + h2*wk2a;
                    float kb = bkb + h0*wk0b + h1*wk1b + h2*wk2b;
                    float p = qa * ka + qb * kb;
                    #pragma unroll
                    for (int o = 32; o > 0; o >>= 1) p += __shfl_xor(p, o);
                    float s = p * scale;
                    float va = bva + h0*wv0a + h1*wv1a + h2*wv2a;
                    float vb = bvb + h0*wv0b + h1*wv1b + h2*wv2b;
                    float mn = fmaxf(m, s);
                    float rs = expf(m - mn);    // first iter: exp(-inf)=0
                    float ws = expf(s - mn);
                    l    = l * rs + ws;
                    acca = acca * rs + ws * va;
                    accb = accb * rs + ws * vb;
                    m = mn;
                }
            }
            float inv = 1.f / l;
            *(u32*)&X[lrow][d0] = pack2bf(acca * inv, accb * inv);
        }
    }
    __syncthreads();

    // ================= MFMA MLP phase =================
    const s16x8* Bp = (const s16x8*)Wpk;
    float h[2][4];
    f32x4 acc[2];
    const f32x4 zero = {0.f, 0.f, 0.f, 0.f};

    // layer0: [16x128] @ [128x256]
    #pragma unroll
    for (int nt = 0; nt < 2; ++nt) acc[nt] = zero;
    #pragma unroll
    for (int kt = 0; kt < 4; ++kt) {
        s16x8 a = *(const s16x8*)&X[c][kt * 32 + q * 8];
        #pragma unroll
        for (int nt = 0; nt < 2; ++nt) {
            s16x8 b = Bp[((w * 2 + nt) * 4 + kt) * 64 + lane];
            acc[nt] = __builtin_amdgcn_mfma_f32_16x16x32_bf16(a, b, acc[nt], 0, 0, 0);
        }
    }
    #pragma unroll
    for (int nt = 0; nt < 2; ++nt) {
        float bb = b0[colb + nt * 16];
        #pragma unroll
        for (int rg = 0; rg < 4; ++rg) h[nt][rg] = acc[nt][rg] + bb;
    }

    // res blocks
    for (int ir = 0; ir < N_RES; ++ir) {
        float part[4];
        #pragma unroll
        for (int rg = 0; rg < 4; ++rg) {
            part[rg] = h[0][rg] * h[0][rg] + h[1][rg] * h[1][rg];
            #pragma unroll
            for (int o = 1; o < 16; o <<= 1) part[rg] += __shfl_xor(part[rg], o);
        }
        if (c == 0) {
            #pragma unroll
            for (int rg = 0; rg < 4; ++rg) red[w][q * 4 + rg] = part[rg];
        }
        __syncthreads();   // red visible; all waves past previous X reads
        float sc4[4];
        #pragma unroll
        for (int rg = 0; rg < 4; ++rg) {
            int rr = q * 4 + rg;
            float ms = (red[0][rr] + red[1][rr] + red[2][rr] + red[3][rr]
                      + red[4][rr] + red[5][rr] + red[6][rr] + red[7][rr]) * (1.f / HID);
            sc4[rg] = rsqrtf(ms + EPS);
        }
        #pragma unroll
        for (int nt = 0; nt < 2; ++nt) {
            float gg = rms_w[ir * HID + colb + nt * 16];
            #pragma unroll
            for (int rg = 0; rg < 4; ++rg)
                X[q * 4 + rg][colb + nt * 16] = f2bf(h[nt][rg] * sc4[rg] * gg);
        }
        __syncthreads();   // hn visible

        const s16x8* Br = Bp + 4096 + ir * 8192;
        #pragma unroll
        for (int nt = 0; nt < 2; ++nt) acc[nt] = zero;
        #pragma unroll
        for (int kt = 0; kt < 8; ++kt) {
            s16x8 a = *(const s16x8*)&X[c][kt * 32 + q * 8];
            #pragma unroll
            for (int nt = 0; nt < 2; ++nt) {
                s16x8 b = Br[((w * 2 + nt) * 8 + kt) * 64 + lane];
                acc[nt] = __builtin_amdgcn_mfma_f32_16x16x32_bf16(a, b, acc[nt], 0, 0, 0);
            }
        }
        #pragma unroll
        for (int nt = 0; nt < 2; ++nt) {
            float bb = bres[ir * HID + colb + nt * 16];
            #pragma unroll
            for (int rg = 0; rg < 4; ++rg) h[nt][rg] += fmaxf(acc[nt][rg] + bb, 0.f);
        }
    }

    // logits
    {
        float wo0 = Wout[colb], wo1 = Wout[colb + 16];
        float part[4];
        #pragma unroll
        for (int rg = 0; rg < 4; ++rg) {
            part[rg] = h[0][rg] * wo0 + h[1][rg] * wo1;
            #pragma unroll
            for (int o = 1; o < 16; o <<= 1) part[rg] += __shfl_xor(part[rg], o);
        }
        if (c == 0) {
            #pragma unroll
            for (int rg = 0; rg < 4; ++rg) red[w][q * 4 + rg] = part[rg];
        }
        __syncthreads();
        if (tid < 16) {
            float s = bout[0];
            #pragma unroll
            for (int w2 = 0; w2 < 8; ++w2) s += red[w2][tid];
            logits[base + tid] = s;
        }
    }
}

// ---- scatter-softmax over edge buckets: one wave per edge ----
__global__ __launch_bounds__(256) void k_segsoft(
        const float* __restrict__ logits, const int* __restrict__ e_off,
        const int* __restrict__ e_cnt, const int* __restrict__ mem_e,
        float* __restrict__ out) {
    int e = (blockIdx.x * 256 + threadIdx.x) >> 6;
    int lane = threadIdx.x & 63;
    int off = e_off[e], cnt = e_cnt[e];
    float mx = -INFINITY;
    for (int i = lane; i < cnt; i += 64) mx = fmaxf(mx, logits[mem_e[off + i]]);
    #pragma unroll
    for (int o = 32; o > 0; o >>= 1) mx = fmaxf(mx, __shfl_xor(mx, o));
    float s = 0.f;
    for (int i = lane; i < cnt; i += 64) s += expf(logits[mem_e[off + i]] - mx);
    #pragma unroll
    for (int o = 32; o > 0; o >>= 1) s += __shfl_xor(s, o);
    float inv = 1.f / s;
    for (int i = lane; i < cnt; i += 64) {
        int m = mem_e[off + i];
        out[m] = expf(logits[m] - mx) * inv;
    }
}

extern "C" void kernel_launch(void* const* d_in, const int* in_sizes, int n_in,
                              void* d_out, int out_size, void* d_ws, size_t ws_size,
                              hipStream_t stream) {
    const float* ef   = (const float*)d_in[0];
    const int*   eids = (const int*)d_in[1];
    const int*   tri  = (const int*)d_in[2];
    const float* Wq = (const float*)d_in[3];
    const float* bq = (const float*)d_in[4];
    const float* Wk = (const float*)d_in[5];
    const float* bk = (const float*)d_in[6];
    const float* Wv = (const float*)d_in[7];
    const float* bv = (const float*)d_in[8];
    const float* W0 = (const float*)d_in[9];
    const float* b0 = (const float*)d_in[10];
    const float* rms_w = (const float*)d_in[11];
    const float* Wres  = (const float*)d_in[12];
    const float* bres  = (const float*)d_in[13];
    const float* Wout  = (const float*)d_in[14];
    const float* bout  = (const float*)d_in[15];
    float* out = (float*)d_out;

    char* ws = (char*)d_ws;
    float* logits  = (float*)(ws + OFF_LOGITS);
    int*   tri_off = (int*)(ws + OFF_TRIOFF);
    int*   tri_cnt = (int*)(ws + OFF_TRICNT);
    int*   mem_t   = (int*)(ws + OFF_MEMT);
    int*   e_off   = (int*)(ws + OFF_EOFF);
    int*   e_cnt   = (int*)(ws + OFF_ECNT);
    int*   mem_e   = (int*)(ws + OFF_MEME);
    u16*   Wpk     = (u16*)(ws + OFF_WPK);

    hipLaunchKernelGGL(k_setup, dim3(21), dim3(1024), 0, stream,
                       tri, eids, W0, Wres,
                       tri_off, tri_cnt, mem_t, e_off, e_cnt, mem_e, Wpk);
    hipLaunchKernelGGL(k_fused, dim3(N / 16), dim3(512), 0, stream,
                       ef, tri, Wq, bq, Wk, bk, Wv, bv,
                       tri_off, tri_cnt, mem_t,
                       b0, rms_w, bres, Wout, bout, Wpk, logits);
    hipLaunchKernelGGL(k_segsoft, dim3(N_EDGE / 4), dim3(256), 0, stream,
                       logits, e_off, e_cnt, mem_e, out);
}